// Round 10
// baseline (226.311 us; speedup 1.0000x reference)
//
#include <hip/hip_runtime.h>
#include <math.h>
#include <stdint.h>

#define NDIM   12
#define KDIM   1024
#define BT_TOT 1024
#define M_TOT  (BT_TOT * NDIM)       // 12288
#define OUT_MAIN (M_TOT * KDIM)      // 12582912
#define MASK_TH 0.4f                 // 0.005 * 80
#define LN_EPS 1e-5f

typedef float f32x4 __attribute__((ext_vector_type(4)));
typedef short bf16x8 __attribute__((ext_vector_type(8)));
typedef short bf16x4 __attribute__((ext_vector_type(4)));

__device__ __forceinline__ float bf2f(unsigned short u) {
    return __uint_as_float(((unsigned int)u) << 16);
}
__device__ __forceinline__ unsigned short f2bf(float f) {
    unsigned int u = __float_as_uint(f);
    return (unsigned short)((u + 0x7FFFu + ((u >> 16) & 1u)) >> 16);   // RNE
}
__device__ __forceinline__ void gld16(const void* g, void* l) {
    __builtin_amdgcn_global_load_lds(
        (const __attribute__((address_space(1))) unsigned int*)g,
        (__attribute__((address_space(3))) unsigned int*)l, 16, 0, 0);
}

// ---- K0: ALL preprocessing in one launch -----------------------------------
// bid [0,64):      Mt = wph @ wth^T (fp32 in, bf16 MFMA, 128x128 tiles)
// bid [64,6208):   x [B,C,T,N] -> featB [B*768][1024] bf16 (64c x 32p tiles)
// bid [6208,7232): transpose wg -> wgT [o][c] bf16
// bid [7232,7488): vbuf = wph @ b_theta (wave per row)
__global__ __launch_bounds__(256)
void prep_kernel(const float* __restrict__ x,   const float* __restrict__ wth,
                 const float* __restrict__ wph, const float* __restrict__ bth,
                 const float* __restrict__ wg,
                 unsigned short* __restrict__ wgT, float* __restrict__ vbuf,
                 unsigned short* __restrict__ featB, unsigned short* __restrict__ MtB)
{
    const int bid = blockIdx.x, tid = threadIdx.x;
    __shared__ __align__(16) char ldsb[16384];

    if (bid < 64) {                          // ---- Mt GEMM (128x128, BK=32)
        const int m0 = (bid >> 3) * 128, n0 = (bid & 7) * 128;
        const int lane = tid & 63, wid = tid >> 6;
        const int wr = wid >> 1, wc = wid & 1;
        unsigned short* As = (unsigned short*)ldsb;     // 128*32
        unsigned short* Bs = As + 4096;                 // 128*32
        f32x4 acc[4][4] = {};
        const int row = tid >> 1, half = tid & 1;

        for (int k0 = 0; k0 < KDIM; k0 += 32) {
            const float* ga = wph + (size_t)(m0 + row) * KDIM + k0 + half * 16;
            const float* gb = wth + (size_t)(n0 + row) * KDIM + k0 + half * 16;
            unsigned short pa[16], pb[16];
            #pragma unroll
            for (int j = 0; j < 4; ++j) {
                const float4 va = ((const float4*)ga)[j];
                const float4 vb = ((const float4*)gb)[j];
                pa[j*4+0] = f2bf(va.x); pa[j*4+1] = f2bf(va.y);
                pa[j*4+2] = f2bf(va.z); pa[j*4+3] = f2bf(va.w);
                pb[j*4+0] = f2bf(vb.x); pb[j*4+1] = f2bf(vb.y);
                pb[j*4+2] = f2bf(vb.z); pb[j*4+3] = f2bf(vb.w);
            }
            const int le = row * 32 + half * 16;
            *(uint4*)&As[le]     = ((const uint4*)pa)[0];
            *(uint4*)&As[le + 8] = ((const uint4*)pa)[1];
            *(uint4*)&Bs[le]     = ((const uint4*)pb)[0];
            *(uint4*)&Bs[le + 8] = ((const uint4*)pb)[1];
            __syncthreads();

            bf16x8 af[4], bfr[4];
            const int rA = wr * 64 + (lane & 15);
            const int rB = wc * 64 + (lane & 15);
            const int kq = (lane >> 4) * 8;
            #pragma unroll
            for (int mi = 0; mi < 4; ++mi)
                af[mi] = *(const bf16x8*)&As[(rA + mi * 16) * 32 + kq];
            #pragma unroll
            for (int ni = 0; ni < 4; ++ni)
                bfr[ni] = *(const bf16x8*)&Bs[(rB + ni * 16) * 32 + kq];
            #pragma unroll
            for (int mi = 0; mi < 4; ++mi)
                #pragma unroll
                for (int ni = 0; ni < 4; ++ni)
                    acc[mi][ni] = __builtin_amdgcn_mfma_f32_16x16x32_bf16(
                        af[mi], bfr[ni], acc[mi][ni], 0, 0, 0);
            __syncthreads();
        }
        // C/D: col=lane&15, row=(lane>>4)*4+reg
        #pragma unroll
        for (int mi = 0; mi < 4; ++mi) {
            const int gr0 = m0 + wr * 64 + mi * 16 + ((tid & 63) >> 4) * 4;
            #pragma unroll
            for (int ni = 0; ni < 4; ++ni) {
                const int gc = n0 + wc * 64 + ni * 16 + (tid & 15);
                const f32x4 v = acc[mi][ni];
                #pragma unroll
                for (int reg = 0; reg < 4; ++reg)
                    MtB[(size_t)(gr0 + reg) * KDIM + gc] = f2bf(v[reg]);
            }
        }
    } else if (bid < 6208) {                 // ---- feat transpose 64c x 32p
        float (*tileF)[33] = (float(*)[33])ldsb;
        const int b4 = bid - 64;
        const int px = b4 % 24;
        const int rest = b4 / 24;
        const int cx = rest & 15, b = rest >> 4;
        const int p0 = px * 32, c0 = cx * 64;
        const float* src = x + (size_t)b * KDIM * 768;
        #pragma unroll
        for (int i = 0; i < 8; ++i) {
            const int cl = (tid >> 5) + i * 8;
            tileF[cl][tid & 31] = src[(size_t)(c0 + cl) * 768 + p0 + (tid & 31)];
        }
        __syncthreads();
        unsigned short* dst = featB + ((size_t)b * 768 + p0) * KDIM;
        #pragma unroll
        for (int i = 0; i < 8; ++i) {
            const int pp = (tid >> 6) + i * 4;
            const int cl = tid & 63;
            dst[(size_t)pp * KDIM + c0 + cl] = f2bf(tileF[cl][pp]);
        }
    } else if (bid < 7232) {                 // ---- transpose wg
        float (*tileF)[33] = (float(*)[33])ldsb;
        const int b2 = bid - 6208;
        const int o0 = (b2 & 31) * 32, c0 = (b2 >> 5) * 32;
        const int tx = tid & 31, ty = tid >> 5;
        #pragma unroll
        for (int i = 0; i < 4; ++i) {
            const int r = ty + i * 8;
            tileF[r][tx] = wg[(size_t)(c0 + r) * KDIM + o0 + tx];
        }
        __syncthreads();
        #pragma unroll
        for (int i = 0; i < 4; ++i) {
            const int r = ty + i * 8;
            wgT[(size_t)(o0 + r) * KDIM + c0 + tx] = f2bf(tileF[tx][r]);
        }
    } else {                                 // ---- vbuf = wph @ b_theta
        const int b3 = bid - 7232;
        const int lane = tid & 63, w = tid >> 6;
        const int j = b3 * 4 + w;
        const float4* row = (const float4*)(wph + (size_t)j * KDIM);
        const float4* bt4 = (const float4*)bth;
        float s = 0.f;
        #pragma unroll
        for (int i = 0; i < 4; ++i) {
            const float4 a = row[lane + i * 64], b = bt4[lane + i * 64];
            s += a.x * b.x + a.y * b.y + a.z * b.z + a.w * b.w;
        }
        #pragma unroll
        for (int msk = 32; msk >= 1; msk >>= 1) s += __shfl_xor(s, msk, 64);
        if (lane == 0) vbuf[j] = s;
    }
}

// ---- K1: C[M,1024] = A[M,1024] @ B^T, bf16 MFMA, BK=64, swizzled LDS -------
// Staging (rule #21): linear LDS dest, source chunk pre-swizzled ^ (row&7),
// ds_read applies the same XOR. Grid 1536: bid&7 = XCD slice (A-panel reuse).
__global__ __launch_bounds__(256)
void gemm_kernel(const unsigned short* __restrict__ A,
                 const unsigned short* __restrict__ B0, const unsigned short* __restrict__ B1,
                 unsigned short* __restrict__ C0, unsigned short* __restrict__ C1)
{
    const int bid = blockIdx.x;
    const int c = bid & 7, s = bid >> 3;
    const int n = s & 7, mm = (s >> 3) % 12, z = s / 96;
    const int m0 = (c * 12 + mm) * 128, n0 = n * 128;
    const unsigned short* B = z ? B1 : B0;
    unsigned short* C       = z ? C1 : C0;

    const int tid = threadIdx.x, lane = tid & 63, wid = tid >> 6;
    const int wr = wid >> 1, wc = wid & 1;

    __shared__ __align__(16) unsigned short As[128 * 64];   // 16 KB
    __shared__ __align__(16) unsigned short Bs[128 * 64];   // 16 KB

    f32x4 acc[4][4] = {};

    const int srow_w = wid * 8 + (lane >> 3);   // + i*32
    const int schunk = lane & 7;

    for (int k0 = 0; k0 < KDIM; k0 += 64) {
        #pragma unroll
        for (int i = 0; i < 4; ++i) {
            const int row = srow_w + i * 32;
            const int gchunk = schunk ^ (row & 7);
            const char* srcA = (const char*)A + ((size_t)(m0 + row) * KDIM + k0) * 2 + gchunk * 16;
            const char* srcB = (const char*)B + ((size_t)(n0 + row) * KDIM + k0) * 2 + gchunk * 16;
            char* la = (char*)As + i * 4096 + wid * 1024;
            char* lb = (char*)Bs + i * 4096 + wid * 1024;
            gld16(srcA, la);
            gld16(srcB, lb);
        }
        __syncthreads();

        #pragma unroll
        for (int ks = 0; ks < 2; ++ks) {
            bf16x8 af[4], bfr[4];
            const int cch = ks * 4 + (lane >> 4);
            #pragma unroll
            for (int mi = 0; mi < 4; ++mi) {
                const int r = wr * 64 + (lane & 15) + mi * 16;
                af[mi] = *(const bf16x8*)((const char*)As + r * 128 + ((cch ^ (r & 7)) * 16));
            }
            #pragma unroll
            for (int ni = 0; ni < 4; ++ni) {
                const int r = wc * 64 + (lane & 15) + ni * 16;
                bfr[ni] = *(const bf16x8*)((const char*)Bs + r * 128 + ((cch ^ (r & 7)) * 16));
            }
            #pragma unroll
            for (int mi = 0; mi < 4; ++mi)
                #pragma unroll
                for (int ni = 0; ni < 4; ++ni)
                    acc[mi][ni] = __builtin_amdgcn_mfma_f32_16x16x32_bf16(
                        af[mi], bfr[ni], acc[mi][ni], 0, 0, 0);
        }
        __syncthreads();
    }

    // C/D layout: col=lane&15, row=(lane>>4)*4+reg  [m89/m91]
    #pragma unroll
    for (int mi = 0; mi < 4; ++mi) {
        const int gr0 = m0 + wr * 64 + mi * 16 + (lane >> 4) * 4;
        #pragma unroll
        for (int ni = 0; ni < 4; ++ni) {
            const int gc = n0 + wc * 64 + ni * 16 + (lane & 15);
            const f32x4 v = acc[mi][ni];
            #pragma unroll
            for (int reg = 0; reg < 4; ++reg)
                C[(size_t)(gr0 + reg) * KDIM + gc] = f2bf(v[reg]);
        }
    }
}

// ---- K2: fused logits(MFMA)+q + mask/softmax + agg2 = rel@H + LN + ReLU ----
// Frame mapping f = (bid&7)*128 + bid>>3 aligns each frame with the XCD whose
// L2 just produced its G/H strip (gemm wrote m-panel c*1536.. on XCD c).
__global__ __launch_bounds__(256)
void relf_kernel(const unsigned short* __restrict__ G,
                 const unsigned short* __restrict__ featB,
                 const unsigned short* __restrict__ H,
                 const float* __restrict__ Abox, const float* __restrict__ vbuf,
                 const float* __restrict__ lnw, const float* __restrict__ lnb,
                 float* __restrict__ out)
{
    const int bid = blockIdx.x;
    const int f = ((bid & 7) << 7) + (bid >> 3);
    const int tid = threadIdx.x, lane = tid & 63, w = tid >> 6;
    __shared__ float Lred[4][16][16];
    __shared__ float relS[12][12];
    __shared__ float cxS[12], cyS[12], sqS[12];
    __shared__ float qred[4][12];
    __shared__ float rs[2][256];

    if (tid < 12) {
        const float4 box = *(const float4*)(Abox + ((size_t)f * 12 + tid) * 4);
        const float cx = (box.x + box.z) * 0.5f, cy = (box.y + box.w) * 0.5f;
        cxS[tid] = cx; cyS[tid] = cy; sqS[tid] = cx * cx + cy * cy;
    }

    // logits = G . feat^T via MFMA; q[m]=feat[m].v folded into the b-frags.
    // Pad rows 12..15 with row 0 (their output rows/cols are discarded).
    const int r = lane & 15, rr = r < 12 ? r : 0;
    const int kq = (lane >> 4) * 8;
    const unsigned short* gG = G + (size_t)(f * 12 + rr) * KDIM;
    const unsigned short* gF = featB + (size_t)(f * 12 + rr) * KDIM;
    f32x4 acc = {};
    float qp = 0.f;
    #pragma unroll
    for (int s8 = 0; s8 < 8; ++s8) {
        const int k0 = (w * 8 + s8) * 32 + kq;
        const bf16x8 a = *(const bf16x8*)(gG + k0);
        const bf16x8 b = *(const bf16x8*)(gF + k0);
        acc = __builtin_amdgcn_mfma_f32_16x16x32_bf16(a, b, acc, 0, 0, 0);
        const float4 v0 = *(const float4*)(vbuf + k0);
        const float4 v1 = *(const float4*)(vbuf + k0 + 4);
        qp += bf2f((unsigned short)b[0]) * v0.x + bf2f((unsigned short)b[1]) * v0.y
            + bf2f((unsigned short)b[2]) * v0.z + bf2f((unsigned short)b[3]) * v0.w
            + bf2f((unsigned short)b[4]) * v1.x + bf2f((unsigned short)b[5]) * v1.y
            + bf2f((unsigned short)b[6]) * v1.z + bf2f((unsigned short)b[7]) * v1.w;
    }
    qp += __shfl_xor(qp, 16, 64);
    qp += __shfl_xor(qp, 32, 64);
    if (lane < 12) qred[w][lane] = qp;
    {
        const int row0 = (lane >> 4) * 4, col = lane & 15;
        #pragma unroll
        for (int reg = 0; reg < 4; ++reg) Lred[w][row0 + reg][col] = acc[reg];
    }
    __syncthreads();

    if (tid < 12) {
        const int n = tid;
        float l[12], mx = -3.4e38f;
        #pragma unroll
        for (int m = 0; m < 12; ++m) {
            const float L = Lred[0][n][m] + Lred[1][n][m] + Lred[2][n][m] + Lred[3][n][m];
            const float qm = qred[0][m] + qred[1][m] + qred[2][m] + qred[3][m];
            float val = (L + qm) * 0.03125f;     // 1/sqrt(1024); row/const bias cancel
            const float d2 = sqS[n] - 2.f * (cxS[n] * cxS[m] + cyS[n] * cyS[m]) + sqS[m];
            const float dist = sqrtf(fmaxf(d2, 0.f));
            if (dist > MASK_TH) val = -INFINITY;
            l[m] = val; mx = fmaxf(mx, val);
        }
        float s = 0.f, e[12];
        #pragma unroll
        for (int m = 0; m < 12; ++m) { e[m] = expf(l[m] - mx); s += e[m]; }
        const float inv = 1.f / s;
        float* orel = out + (size_t)OUT_MAIN + (size_t)f * 144 + n * 12;
        #pragma unroll
        for (int m = 0; m < 12; ++m) {
            const float rv = e[m] * inv;
            relS[n][m] = rv;
            orel[m] = rv;
        }
    }
    __syncthreads();

    // agg2[n][c] = sum_m rel[n][m] * H[m][c];  thread owns c = tid*4 .. tid*4+3
    const int c0 = tid * 4;
    float h[12][4];
    #pragma unroll
    for (int m = 0; m < 12; ++m) {
        const bf16x4 h4 = *(const bf16x4*)(H + (size_t)(f * 12 + m) * KDIM + c0);
        #pragma unroll
        for (int j = 0; j < 4; ++j) h[m][j] = bf2f((unsigned short)h4[j]);
    }
    float a2[12][4];
    float s = 0.f, s2 = 0.f;
    #pragma unroll
    for (int n = 0; n < 12; ++n) {
        float rn[12];
        #pragma unroll
        for (int m = 0; m < 12; ++m) rn[m] = relS[n][m];
        #pragma unroll
        for (int j = 0; j < 4; ++j) {
            float a = 0.f;
            #pragma unroll
            for (int m = 0; m < 12; ++m) a = fmaf(rn[m], h[m][j], a);
            a2[n][j] = a; s += a; s2 += a * a;
        }
    }
    rs[0][tid] = s; rs[1][tid] = s2;
    __syncthreads();
    for (int o = 128; o > 0; o >>= 1) {
        if (tid < o) { rs[0][tid] += rs[0][tid + o]; rs[1][tid] += rs[1][tid + o]; }
        __syncthreads();
    }
    const float mu = rs[0][0] * (1.f / 12288.f);
    const float var = rs[1][0] * (1.f / 12288.f) - mu * mu;
    const float rstd = rsqrtf(var + LN_EPS);

    #pragma unroll
    for (int n = 0; n < 12; ++n) {
        const float4 wv = *(const float4*)(lnw + (size_t)n * KDIM + c0);
        const float4 bv = *(const float4*)(lnb + (size_t)n * KDIM + c0);
        float4 ov;
        ov.x = fmaxf(fmaf((a2[n][0] - mu) * rstd, wv.x, bv.x), 0.f);
        ov.y = fmaxf(fmaf((a2[n][1] - mu) * rstd, wv.y, bv.y), 0.f);
        ov.z = fmaxf(fmaf((a2[n][2] - mu) * rstd, wv.z, bv.z), 0.f);
        ov.w = fmaxf(fmaf((a2[n][3] - mu) * rstd, wv.w, bv.w), 0.f);
        *(float4*)(out + (size_t)(f * 12 + n) * KDIM + c0) = ov;
    }
}

extern "C" void kernel_launch(void* const* d_in, const int* in_sizes, int n_in,
                              void* d_out, int out_size, void* d_ws, size_t ws_size,
                              hipStream_t stream) {
    const float* x   = (const float*)d_in[0];
    const float* A   = (const float*)d_in[1];
    const float* wth = (const float*)d_in[2];
    const float* bth = (const float*)d_in[3];
    const float* wph = (const float*)d_in[4];
    // bph: row-bias term cancels in softmax
    const float* wg  = (const float*)d_in[6];
    const float* lnw = (const float*)d_in[7];
    const float* lnb = (const float*)d_in[8];
    float* out = (float*)d_out;

    char* ws = (char*)d_ws;
    const size_t MB = 1ull << 20;
    unsigned short* featB = (unsigned short*)(ws);            // 24 MB
    unsigned short* G     = (unsigned short*)(ws + 24 * MB);  // 24 MB
    unsigned short* H     = (unsigned short*)(ws + 48 * MB);  // 24 MB
    unsigned short* wgT   = (unsigned short*)(ws + 72 * MB);  // 2 MB
    unsigned short* MtB   = (unsigned short*)(ws + 74 * MB);  // 2 MB
    float* vbuf = (float*)(ws + 76 * MB);                     // 4 KB

    prep_kernel<<<7488, 256, 0, stream>>>(x, wth, wph, bth, wg,
                                          wgT, vbuf, featB, MtB);
    // G = feat @ Mt^T (z=0), H = feat @ Wg (z=1); XCD-swizzled 1D grid
    gemm_kernel<<<1536, 256, 0, stream>>>(featB, MtB, wgT, G, H);
    relf_kernel<<<BT_TOT, 256, 0, stream>>>(G, featB, H, A, vbuf, lnw, lnb, out);
}